// Round 2
// baseline (344.016 us; speedup 1.0000x reference)
//
#include <hip/hip_runtime.h>
#include <math.h>

// Problem constants (fixed by setup_inputs)
#define W_ 192
#define H_ 192
#define D_ 160
#define B_ 2
#define TILE 16
#define HALO 20           // TILE + 4 (window 5, pad 2)
#define CHUNK 20          // z-planes of output per block (8 chunks per batch)
#define PLANES (CHUNK + 4)
#define NTOT 11796480.0f  // 2*1*160*192*192

struct Q { float ss, tt, s2, t2, st; };

__global__ __launch_bounds__(256, 8) void lncc_main(const float* __restrict__ src,
                                                    const float* __restrict__ tgt,
                                                    float* __restrict__ acc) {
    __shared__ float2 raw[HALO][HALO + 1];   // {s,t} halo tile, pad breaks 20-stride
    __shared__ float4 rs4[HALO][TILE + 1];   // x-rowsums {Σs,Σt,Σs²,Σt²}
    __shared__ float  rs1[HALO][TILE + 1];   // x-rowsums {Σst}
    __shared__ float  wsum[4];

    const int tx  = threadIdx.x, ty = threadIdx.y;
    const int tid = ty * TILE + tx;
    const int bz  = blockIdx.z;
    const int b   = bz >> 3;                 // D_/CHUNK == 8 chunks per batch
    const int z0  = (bz & 7) * CHUNK;
    const int bx0 = blockIdx.x * TILE - 2;
    const int by0 = blockIdx.y * TILE - 2;

    Q ring[5] = {{0,0,0,0,0},{0,0,0,0,0},{0,0,0,0,0},{0,0,0,0,0},{0,0,0,0,0}};
    Q zs = {0,0,0,0,0};
    float lsum = 0.0f;

    #pragma unroll   // full unroll: ring[i%5] indices become static -> no scratch
    for (int i = 0; i < PLANES; ++i) {
        const int zp = z0 - 2 + i;
        Q ys = {0,0,0,0,0};
        if (zp >= 0 && zp < D_) {            // uniform per block -> barriers safe
            const size_t planeBase = (size_t)(b * D_ + zp) * (size_t)(H_ * W_);
            // ---- stage raw {s,t} halo tile ----
            {
                int f = tid;
                #pragma unroll
                for (int rep = 0; rep < 2; ++rep, f += 256) {
                    if (f < HALO * HALO) {
                        int r  = f / HALO;
                        int c  = f - r * HALO;
                        int gy = by0 + r, gx = bx0 + c;
                        float sv = 0.0f, tv = 0.0f;
                        if ((unsigned)gx < (unsigned)W_ && (unsigned)gy < (unsigned)H_) {
                            size_t idx = planeBase + (size_t)gy * W_ + (size_t)gx;
                            sv = src[idx];
                            tv = tgt[idx];
                        }
                        raw[r][c] = make_float2(sv, tv);
                    }
                }
            }
            __syncthreads();   // raw visible; also orders prev ysum reads vs rs writes
            // ---- phase 1: x-direction 5-tap rowsums at 20x16 positions ----
            {
                int p = tid;
                #pragma unroll
                for (int rep = 0; rep < 2; ++rep, p += 256) {
                    if (p < HALO * TILE) {
                        int ry = p >> 4, rx = p & 15;
                        float a0 = 0, a1 = 0, a2 = 0, a3 = 0, a4 = 0;
                        #pragma unroll
                        for (int dx = 0; dx < 5; ++dx) {
                            float2 v = raw[ry][rx + dx];
                            a0 += v.x;
                            a1 += v.y;
                            a2 = fmaf(v.x, v.x, a2);
                            a3 = fmaf(v.y, v.y, a3);
                            a4 = fmaf(v.x, v.y, a4);
                        }
                        rs4[ry][rx] = make_float4(a0, a1, a2, a3);
                        rs1[ry][rx] = a4;
                    }
                }
            }
            __syncthreads();   // rs visible; raw free to overwrite next plane
            // ---- phase 2: y-direction 5-tap sum of rowsums ----
            #pragma unroll
            for (int dy = 0; dy < 5; ++dy) {
                float4 a = rs4[ty + dy][tx];
                float  g = rs1[ty + dy][tx];
                ys.ss += a.x;
                ys.tt += a.y;
                ys.s2 += a.z;
                ys.t2 += a.w;
                ys.st += g;
            }
        }
        // ---- z sliding window: zs = sum of last 5 plane-sums ----
        const int slot = i % 5;              // static after full unroll
        zs.ss += ys.ss - ring[slot].ss;
        zs.tt += ys.tt - ring[slot].tt;
        zs.s2 += ys.s2 - ring[slot].s2;
        zs.t2 += ys.t2 - ring[slot].t2;
        zs.st += ys.st - ring[slot].st;
        ring[slot] = ys;

        if (i >= 4) {                        // output voxel z = zp-2 complete
            const float inv = 1.0f / 125.0f;
            float ms = zs.ss * inv, mt = zs.tt * inv;
            float vs = fmaf(-ms, ms, zs.s2 * inv);
            float vt = fmaf(-mt, mt, zs.t2 * inv);
            float cr = fmaf(-ms, mt, zs.st * inv);
            float den = fmaf(vs, vt, 1e-5f);
            lsum = fmaf(cr * cr, __builtin_amdgcn_rcpf(den), lsum);
        }
    }

    // block reduction: wave shuffle, then across the 4 waves via LDS
    #pragma unroll
    for (int off = 32; off > 0; off >>= 1)
        lsum += __shfl_down(lsum, off, 64);
    if ((tid & 63) == 0) wsum[tid >> 6] = lsum;
    __syncthreads();
    if (tid == 0) {
        float t = wsum[0] + wsum[1] + wsum[2] + wsum[3];
        atomicAdd(acc, t);
    }
}

__global__ void lncc_zero(float* acc) { *acc = 0.0f; }

__global__ void lncc_finalize(const float* __restrict__ acc, float* __restrict__ out) {
    float loss = 1.0f - (*acc) * (1.0f / NTOT);
    if (isnan(loss) || isinf(loss)) loss = 1.0f;
    *out = loss;
}

extern "C" void kernel_launch(void* const* d_in, const int* in_sizes, int n_in,
                              void* d_out, int out_size, void* d_ws, size_t ws_size,
                              hipStream_t stream) {
    const float* src = (const float*)d_in[0];
    const float* tgt = (const float*)d_in[1];
    float* out = (float*)d_out;
    float* acc = (float*)d_ws;   // one fp32 accumulator in workspace

    lncc_zero<<<dim3(1), dim3(1), 0, stream>>>(acc);

    dim3 grid(W_ / TILE, H_ / TILE, B_ * (D_ / CHUNK));  // 12 x 12 x 16
    dim3 block(TILE, TILE, 1);
    lncc_main<<<grid, block, 0, stream>>>(src, tgt, acc);

    lncc_finalize<<<dim3(1), dim3(1), 0, stream>>>(acc, out);
}

// Round 3
// 191.086 us; speedup vs baseline: 1.8003x; 1.8003x over previous
//
#include <hip/hip_runtime.h>
#include <math.h>

// Problem constants (fixed by setup_inputs)
#define W_ 192
#define H_ 192
#define D_ 160
#define B_ 2
#define TILE 16
#define HALO 20           // TILE + 4 (window 5, pad 2)
#define CHUNK 20          // z-planes of output per block (8 chunks per batch)
#define PLANES (CHUNK + 4)
#define NTOT 11796480.0f  // 2*1*160*192*192

struct Q { float ss, tt, s2, t2, st; };

__global__ __launch_bounds__(256) void lncc_main(const float* __restrict__ src,
                                                 const float* __restrict__ tgt,
                                                 float* __restrict__ acc) {
    __shared__ float2 raw[HALO][HALO + 1];   // {s,t} halo tile, pad breaks 20-stride
    __shared__ float4 rs4[HALO][TILE + 1];   // x-rowsums {Σs,Σt,Σs²,Σt²}
    __shared__ float  rs1[HALO][TILE + 1];   // x-rowsums {Σst}
    __shared__ float  wsum[4];

    const int tx  = threadIdx.x, ty = threadIdx.y;
    const int tid = ty * TILE + tx;
    const int bz  = blockIdx.z;
    const int b   = bz >> 3;                 // D_/CHUNK == 8 chunks per batch
    const int z0  = (bz & 7) * CHUNK;
    const int bx0 = blockIdx.x * TILE - 2;
    const int by0 = blockIdx.y * TILE - 2;

    // z-ring as NAMED registers rotated by explicit assignment — round-2's
    // ring[i%5] array went to scratch (244 MB WRITE_SIZE); this form is
    // guaranteed register renames (round 1: VGPR=32, WRITE=36 KB).
    Q r0 = {0,0,0,0,0}, r1 = {0,0,0,0,0}, r2 = {0,0,0,0,0},
      r3 = {0,0,0,0,0}, r4 = {0,0,0,0,0};
    Q zs = {0,0,0,0,0};
    float lsum = 0.0f;

    for (int i = 0; i < PLANES; ++i) {       // runtime loop, no unroll needed
        const int zp = z0 - 2 + i;
        Q ys = {0,0,0,0,0};
        if (zp >= 0 && zp < D_) {            // uniform per block -> barriers safe
            const size_t planeBase = (size_t)(b * D_ + zp) * (size_t)(H_ * W_);
            // ---- stage raw {s,t} halo tile ----
            {
                int f = tid;
                #pragma unroll
                for (int rep = 0; rep < 2; ++rep, f += 256) {
                    if (f < HALO * HALO) {
                        int r  = f / HALO;
                        int c  = f - r * HALO;
                        int gy = by0 + r, gx = bx0 + c;
                        float sv = 0.0f, tv = 0.0f;
                        if ((unsigned)gx < (unsigned)W_ && (unsigned)gy < (unsigned)H_) {
                            size_t idx = planeBase + (size_t)gy * W_ + (size_t)gx;
                            sv = src[idx];
                            tv = tgt[idx];
                        }
                        raw[r][c] = make_float2(sv, tv);
                    }
                }
            }
            __syncthreads();   // raw visible; also orders prev phase-2 reads vs rs writes
            // ---- phase 1: x-direction 5-tap rowsums at 20x16 positions ----
            {
                int p = tid;
                #pragma unroll
                for (int rep = 0; rep < 2; ++rep, p += 256) {
                    if (p < HALO * TILE) {
                        int ry = p >> 4, rx = p & 15;
                        float a0 = 0, a1 = 0, a2 = 0, a3 = 0, a4 = 0;
                        #pragma unroll
                        for (int dx = 0; dx < 5; ++dx) {
                            float2 v = raw[ry][rx + dx];
                            a0 += v.x;
                            a1 += v.y;
                            a2 = fmaf(v.x, v.x, a2);
                            a3 = fmaf(v.y, v.y, a3);
                            a4 = fmaf(v.x, v.y, a4);
                        }
                        rs4[ry][rx] = make_float4(a0, a1, a2, a3);
                        rs1[ry][rx] = a4;
                    }
                }
            }
            __syncthreads();   // rs visible; raw free to overwrite next plane
            // ---- phase 2: y-direction 5-tap sum of rowsums ----
            #pragma unroll
            for (int dy = 0; dy < 5; ++dy) {
                float4 a = rs4[ty + dy][tx];
                float  g = rs1[ty + dy][tx];
                ys.ss += a.x;
                ys.tt += a.y;
                ys.s2 += a.z;
                ys.t2 += a.w;
                ys.st += g;
            }
        }
        // ---- z sliding window: zs = sum of last 5 plane-sums ----
        zs.ss += ys.ss - r0.ss;
        zs.tt += ys.tt - r0.tt;
        zs.s2 += ys.s2 - r0.s2;
        zs.t2 += ys.t2 - r0.t2;
        zs.st += ys.st - r0.st;
        r0 = r1; r1 = r2; r2 = r3; r3 = r4; r4 = ys;

        if (i >= 4) {                        // output voxel z = zp-2 complete
            const float inv = 1.0f / 125.0f;
            float ms = zs.ss * inv, mt = zs.tt * inv;
            float vs = fmaf(-ms, ms, zs.s2 * inv);
            float vt = fmaf(-mt, mt, zs.t2 * inv);
            float cr = fmaf(-ms, mt, zs.st * inv);
            float den = fmaf(vs, vt, 1e-5f);
            lsum = fmaf(cr * cr, __builtin_amdgcn_rcpf(den), lsum);
        }
    }

    // block reduction: wave shuffle, then across the 4 waves via LDS
    #pragma unroll
    for (int off = 32; off > 0; off >>= 1)
        lsum += __shfl_down(lsum, off, 64);
    if ((tid & 63) == 0) wsum[tid >> 6] = lsum;
    __syncthreads();
    if (tid == 0) {
        float t = wsum[0] + wsum[1] + wsum[2] + wsum[3];
        atomicAdd(acc, t);
    }
}

__global__ void lncc_zero(float* acc) { *acc = 0.0f; }

__global__ void lncc_finalize(const float* __restrict__ acc, float* __restrict__ out) {
    float loss = 1.0f - (*acc) * (1.0f / NTOT);
    if (isnan(loss) || isinf(loss)) loss = 1.0f;
    *out = loss;
}

extern "C" void kernel_launch(void* const* d_in, const int* in_sizes, int n_in,
                              void* d_out, int out_size, void* d_ws, size_t ws_size,
                              hipStream_t stream) {
    const float* src = (const float*)d_in[0];
    const float* tgt = (const float*)d_in[1];
    float* out = (float*)d_out;
    float* acc = (float*)d_ws;   // one fp32 accumulator in workspace

    lncc_zero<<<dim3(1), dim3(1), 0, stream>>>(acc);

    dim3 grid(W_ / TILE, H_ / TILE, B_ * (D_ / CHUNK));  // 12 x 12 x 16
    dim3 block(TILE, TILE, 1);
    lncc_main<<<grid, block, 0, stream>>>(src, tgt, acc);

    lncc_finalize<<<dim3(1), dim3(1), 0, stream>>>(acc, out);
}

// Round 4
// 172.327 us; speedup vs baseline: 1.9963x; 1.1089x over previous
//
#include <hip/hip_runtime.h>
#include <math.h>

// Problem constants (fixed by setup_inputs)
#define W_ 192
#define H_ 192
#define D_ 160
#define B_ 2
#define TILE 16
#define HALO 20           // TILE + 4 (window 5, pad 2)
#define RAWP 21           // raw row stride (odd -> <=3-way banks)
#define RSP  17           // rowsum row stride (odd -> <=2-way banks)
#define CHUNK 20          // z-planes of output per block
#define PLANES (CHUNK + 4)
#define GX 12
#define GY 12
#define GZ 16
#define NBLK (GX * GY * GZ)   // 2304
#define NTOT 11796480.0f      // 2*1*160*192*192

__global__ __launch_bounds__(256) void lncc_main(const float* __restrict__ src,
                                                 const float* __restrict__ tgt,
                                                 float* __restrict__ partial) {
    // SoA float LDS, double-buffered for the 1-barrier/plane pipeline.
    __shared__ float rawS[2][HALO][RAWP];
    __shared__ float rawT[2][HALO][RAWP];
    __shared__ float rsS [2][HALO][RSP];
    __shared__ float rsT [2][HALO][RSP];
    __shared__ float rsS2[2][HALO][RSP];
    __shared__ float rsT2[2][HALO][RSP];
    __shared__ float rsST[2][HALO][RSP];
    __shared__ float wsum[4];

    const int tx  = threadIdx.x, ty = threadIdx.y;
    const int tid = ty * TILE + tx;
    const int bz  = blockIdx.z;
    const int b   = bz >> 3;                 // 8 chunks per batch
    const int z0  = (bz & 7) * CHUNK;
    const int bx0 = blockIdx.x * TILE - 2;   // even -> float2-aligned columns
    const int by0 = blockIdx.y * TILE - 2;

    // ---- staging decode: tid<200 loads one aligned float2 per array ----
    const int  sr  = tid / 10;               // row 0..19
    const int  sc  = (tid - sr * 10) * 2;    // col 0,2,..,18 (pairs never straddle W)
    const int  sgx = bx0 + sc;
    const int  sgy = by0 + sr;
    const bool sW  = (tid < 200);
    const bool sOk = sW && ((unsigned)sgx < (unsigned)W_) && ((unsigned)sgy < (unsigned)H_);
    const size_t sOff = (size_t)sgy * W_ + (size_t)sgx;   // valid only when sOk

    // ---- phase1 decode: 20x16 rowsum positions in two reps ----
    const int  p0y = tid >> 4, px = tid & 15;   // rep0: rows 0..15 (all threads)
    const int  p1y = p0y + 16;                  // rep1: rows 16..19 (tid<64)
    const bool p1  = (tid < 64);

    // z-ring as NAMED registers (arrays go to scratch — round-2 lesson)
    float q0s=0,q0t=0,q0a=0,q0b=0,q0c=0;
    float q1s=0,q1t=0,q1a=0,q1b=0,q1c=0;
    float q2s=0,q2t=0,q2a=0,q2b=0,q2c=0;
    float q3s=0,q3t=0,q3a=0,q3b=0,q3c=0;
    float q4s=0,q4t=0,q4a=0,q4b=0,q4c=0;
    float zS=0,zT=0,zS2=0,zT2=0,zST=0;
    float lsum = 0.0f;

    // phase2: y-sum of rowsums for plane j (rowsums in buffer rbuf) + z-window
    auto phase2 = [&](int rbuf, int j) {
        float yS=0,yT=0,yS2=0,yT2=0,yST=0;
        #pragma unroll
        for (int dy = 0; dy < 5; ++dy) {
            yS  += rsS [rbuf][ty + dy][tx];
            yT  += rsT [rbuf][ty + dy][tx];
            yS2 += rsS2[rbuf][ty + dy][tx];
            yT2 += rsT2[rbuf][ty + dy][tx];
            yST += rsST[rbuf][ty + dy][tx];
        }
        zS += yS - q0s;  zT += yT - q0t;  zS2 += yS2 - q0a;
        zT2 += yT2 - q0b;  zST += yST - q0c;
        q0s=q1s; q0t=q1t; q0a=q1a; q0b=q1b; q0c=q1c;
        q1s=q2s; q1t=q2t; q1a=q2a; q1b=q2b; q1c=q2c;
        q2s=q3s; q2t=q3t; q2a=q3a; q2b=q3b; q2c=q3c;
        q3s=q4s; q3t=q4t; q3a=q4a; q3b=q4b; q3c=q4c;
        q4s=yS;  q4t=yT;  q4a=yS2; q4b=yT2; q4c=yST;
        if (j >= 4) {
            const float inv = 1.0f / 125.0f;
            float ms = zS * inv, mt = zT * inv;
            float vs = fmaf(-ms, ms, zS2 * inv);
            float vt = fmaf(-mt, mt, zT2 * inv);
            float cr = fmaf(-ms, mt, zST * inv);
            float den = fmaf(vs, vt, 1e-5f);
            lsum = fmaf(cr * cr, __builtin_amdgcn_rcpf(den), lsum);
        }
    };

    // ---- prologue: stage plane zp = z0-2 into raw[0] ----
    {
        float2 vS = make_float2(0.f, 0.f), vT = make_float2(0.f, 0.f);
        const int zp = z0 - 2;
        if (zp >= 0 && sOk) {
            const size_t base = (size_t)(b * D_ + zp) * (size_t)(H_ * W_);
            vS = *(const float2*)(src + base + sOff);
            vT = *(const float2*)(tgt + base + sOff);
        }
        if (sW) {
            rawS[0][sr][sc] = vS.x;  rawS[0][sr][sc + 1] = vS.y;
            rawT[0][sr][sc] = vT.x;  rawT[0][sr][sc + 1] = vT.y;
        }
    }

    for (int i = 0; i < PLANES; ++i) {
        const int buf = i & 1;
        __syncthreads();   // the ONLY barrier per plane
        // -- issue global loads for plane i+1 (consumed at loop end) --
        float2 vS = make_float2(0.f, 0.f), vT = make_float2(0.f, 0.f);
        const bool haveNext = (i + 1 < PLANES);
        const int  zpn = z0 - 1 + i;
        if (haveNext && zpn >= 0 && zpn < D_ && sOk) {
            const size_t base = (size_t)(b * D_ + zpn) * (size_t)(H_ * W_);
            vS = *(const float2*)(src + base + sOff);
            vT = *(const float2*)(tgt + base + sOff);
        }
        // -- phase2 for plane i-1 (rowsums written last iteration) --
        if (i >= 1) phase2(buf ^ 1, i - 1);
        // -- phase1 for plane i: x-rowsums raw[buf] -> rs[buf] --
        {
            float a0=0,a1=0,a2=0,a3=0,a4=0;
            #pragma unroll
            for (int dx = 0; dx < 5; ++dx) {
                float s = rawS[buf][p0y][px + dx];
                float t = rawT[buf][p0y][px + dx];
                a0 += s; a1 += t;
                a2 = fmaf(s, s, a2);
                a3 = fmaf(t, t, a3);
                a4 = fmaf(s, t, a4);
            }
            rsS [buf][p0y][px] = a0;
            rsT [buf][p0y][px] = a1;
            rsS2[buf][p0y][px] = a2;
            rsT2[buf][p0y][px] = a3;
            rsST[buf][p0y][px] = a4;
            if (p1) {
                float b0=0,b1=0,b2=0,b3=0,b4=0;
                #pragma unroll
                for (int dx = 0; dx < 5; ++dx) {
                    float s = rawS[buf][p1y][px + dx];
                    float t = rawT[buf][p1y][px + dx];
                    b0 += s; b1 += t;
                    b2 = fmaf(s, s, b2);
                    b3 = fmaf(t, t, b3);
                    b4 = fmaf(s, t, b4);
                }
                rsS [buf][p1y][px] = b0;
                rsT [buf][p1y][px] = b1;
                rsS2[buf][p1y][px] = b2;
                rsT2[buf][p1y][px] = b3;
                rsST[buf][p1y][px] = b4;
            }
        }
        // -- write staged plane i+1 into raw[buf^1] (vmcnt wait lands here) --
        if (haveNext && sW) {
            rawS[buf ^ 1][sr][sc] = vS.x;  rawS[buf ^ 1][sr][sc + 1] = vS.y;
            rawT[buf ^ 1][sr][sc] = vT.x;  rawT[buf ^ 1][sr][sc + 1] = vT.y;
        }
    }
    __syncthreads();
    phase2((PLANES - 1) & 1, PLANES - 1);   // drain the pipeline

    // block reduction -> per-block partial (no atomics, no zero-kernel)
    #pragma unroll
    for (int off = 32; off > 0; off >>= 1)
        lsum += __shfl_down(lsum, off, 64);
    if ((tid & 63) == 0) wsum[tid >> 6] = lsum;
    __syncthreads();
    if (tid == 0) {
        const int bid = (blockIdx.z * GY + blockIdx.y) * GX + blockIdx.x;
        partial[bid] = wsum[0] + wsum[1] + wsum[2] + wsum[3];
    }
}

__global__ __launch_bounds__(256) void lncc_finalize(const float* __restrict__ partial,
                                                     float* __restrict__ out) {
    __shared__ float ws[4];
    const int t = threadIdx.x;
    float s = 0.0f;
    for (int i = t; i < NBLK; i += 256) s += partial[i];
    #pragma unroll
    for (int off = 32; off > 0; off >>= 1) s += __shfl_down(s, off, 64);
    if ((t & 63) == 0) ws[t >> 6] = s;
    __syncthreads();
    if (t == 0) {
        float tot = ws[0] + ws[1] + ws[2] + ws[3];
        float loss = 1.0f - tot * (1.0f / NTOT);
        if (isnan(loss) || isinf(loss)) loss = 1.0f;
        *out = loss;
    }
}

extern "C" void kernel_launch(void* const* d_in, const int* in_sizes, int n_in,
                              void* d_out, int out_size, void* d_ws, size_t ws_size,
                              hipStream_t stream) {
    const float* src = (const float*)d_in[0];
    const float* tgt = (const float*)d_in[1];
    float* out = (float*)d_out;
    float* partial = (float*)d_ws;   // NBLK floats of scratch

    dim3 grid(GX, GY, GZ);           // 12 x 12 x 16 = 2304 blocks
    dim3 block(TILE, TILE, 1);
    lncc_main<<<grid, block, 0, stream>>>(src, tgt, partial);
    lncc_finalize<<<dim3(1), dim3(256), 0, stream>>>(partial, out);
}